// Round 1
// baseline (26932.092 us; speedup 1.0000x reference)
//
#include <hip/hip_runtime.h>
#include <hip/hip_bf16.h>

#define NB 32
#define NBLK 64
#define TT 512
#define DD 20

using bf16x8 = __attribute__((ext_vector_type(8))) short;
using f32x4  = __attribute__((ext_vector_type(4))) float;

// workspace byte offsets (prep output)
#define OFF_WIH0  0          // 1024x20  -> 64 tiles x 1 kt (stride 1024)
#define OFF_WHH0  65536      // 1024x256 -> 64 tiles x 8 kt (stride 8192)
#define OFF_WIH1  589824
#define OFF_WHH1  1114112
#define OFF_WPROJ 1638400    // 20x256 -> 2 tiles x 8 kt
#define OFF_B0    1654784
#define OFF_B1    1658880

// smem layout (bytes)
#define SM_PAN   0        // cinit 64K overlay during init only (weights now stream to VGPR)
#define SM_H0    65536    // 32*264*2 = 16896 (single copy, in-place)
#define SM_H1    82432    // 16896
#define SM_XB    99328    // 32*32*2 = 2048
#define SM_WPS   101376   // 16384 (resident)
#define SM_ZB    117760   // 4096
#define SM_TOTAL 121856

__device__ __forceinline__ float sigf(float x) { return 1.0f / (1.0f + __expf(-x)); }
__device__ __forceinline__ float tanhfast(float x) { return 1.0f - 2.0f / (__expf(2.0f * x) + 1.0f); }

// ---- prep: fp32 weights -> bf16, swizzled into MFMA B-fragment order ----
__global__ void prep_kernel(const float* __restrict__ wih0, const float* __restrict__ whh0,
                            const float* __restrict__ wih1, const float* __restrict__ whh1,
                            const float* __restrict__ wproj,
                            const float* __restrict__ bih0, const float* __restrict__ bhh0,
                            const float* __restrict__ bih1, const float* __restrict__ bhh1,
                            char* __restrict__ ws) {
    int idx = blockIdx.x * 256 + threadIdx.x;
    const float* src;
    __hip_bfloat16* dst;
    int e, N, K, nKt;
    if (idx < 32768)       { e = idx;          src = wih0;  N = 1024; K = 20;  nKt = 1; dst = (__hip_bfloat16*)(ws + OFF_WIH0); }
    else if (idx < 294912) { e = idx - 32768;  src = whh0;  N = 1024; K = 256; nKt = 8; dst = (__hip_bfloat16*)(ws + OFF_WHH0); }
    else if (idx < 557056) { e = idx - 294912; src = wih1;  N = 1024; K = 256; nKt = 8; dst = (__hip_bfloat16*)(ws + OFF_WIH1); }
    else if (idx < 819200) { e = idx - 557056; src = whh1;  N = 1024; K = 256; nKt = 8; dst = (__hip_bfloat16*)(ws + OFF_WHH1); }
    else if (idx < 827392) { e = idx - 819200; src = wproj; N = 20;   K = 256; nKt = 8; dst = (__hip_bfloat16*)(ws + OFF_WPROJ); }
    else if (idx < 828416) { int j = idx - 827392; ((float*)(ws + OFF_B0))[j] = bih0[j] + bhh0[j]; return; }
    else if (idx < 829440) { int j = idx - 828416; ((float*)(ws + OFF_B1))[j] = bih1[j] + bhh1[j]; return; }
    else return;
    int j    = e & 7;
    int lane = (e >> 3) & 63;
    int tile = e >> 9;
    int kt = tile % nKt;
    int nt = tile / nKt;
    int n = nt * 16 + (lane & 15);
    int k = kt * 32 + ((lane >> 4) << 3) + j;
    float v = (n < N && k < K) ? src[n * K + k] : 0.0f;
    dst[e] = __float2bfloat16(v);
}

// ---- persistent decoder: 64 blocks x 512 threads, 32 batch rows/block, 512 steps ----
// Weights stream global -> VGPR directly (each tile consumed by exactly one wave);
// LDS holds only h0/h1/x exchange + resident W_proj. 4 barriers per step.
__global__ __launch_bounds__(512, 1) void decoder_kernel(
    const float* __restrict__ z, const float* __restrict__ w_lh, const float* __restrict__ b_lh,
    const float* __restrict__ w_lc, const float* __restrict__ b_lc,
    const float* __restrict__ b_proj, const char* __restrict__ ws,
    float* __restrict__ out) {

    __shared__ __align__(16) char smem[SM_TOTAL];

    const int tid = threadIdx.x;
    const int b0  = blockIdx.x * NB;

    __hip_bfloat16* h0p = (__hip_bfloat16*)(smem + SM_H0); // [m*264 + u]
    __hip_bfloat16* h1p = (__hip_bfloat16*)(smem + SM_H1);
    __hip_bfloat16* xbh = (__hip_bfloat16*)(smem + SM_XB); // [32][32]

    // ---- init: stage z, zero xb, stage W_proj ----
    {
        float* zbf = (float*)(smem + SM_ZB);
        zbf[tid]       = z[(b0 + (tid >> 5)) * 32 + (tid & 31)];
        int i2 = tid + 512;
        zbf[i2]        = z[(b0 + (i2 >> 5)) * 32 + (i2 & 31)];
        ((unsigned int*)(smem + SM_XB))[tid] = 0;  // 2048 B of zeros
        const bf16x8* sp = (const bf16x8*)(ws + OFF_WPROJ);
        bf16x8* dp = (bf16x8*)(smem + SM_WPS);
        dp[tid] = sp[tid];
        dp[tid + 512] = sp[tid + 512];
    }
    __syncthreads();

    // ---- h/c init (fp32 VALU, K=32): 32 rows x 512 cols ----
    {
        float* cinitf = (float*)smem;            // overlay in (former) panel area: [2][32][256]
        const float* zbf = (const float*)(smem + SM_ZB);
        for (int ii = 0; ii < 32; ii++) {
            int pi = ii * 512 + tid;
            int b = pi >> 9, col = pi & 511;
            float dh = b_lh[col], dc = b_lc[col];
            #pragma unroll 8
            for (int k = 0; k < 32; k++) {
                float zv = zbf[b * 32 + k];
                dh += zv * w_lh[col * 32 + k];
                dc += zv * w_lc[col * 32 + k];
            }
            if (col < 256) { h0p[b * 264 + col]         = __float2bfloat16(dh); cinitf[b * 256 + col]                 = dc; }
            else           { h1p[b * 264 + (col - 256)] = __float2bfloat16(dh); cinitf[8192 + b * 256 + (col - 256)] = dc; }
        }
    }
    __syncthreads();

    const int wv = tid >> 6, ln = tid & 63;
    const int l15 = ln & 15, lq = ln >> 4;
    const int lnoff = ln * 16;

    // c-state lane-local: m = mt*16 + lq*4 + r, u = wv*32 + h*16 + l15
    float c0r[2][2][4], c1r[2][2][4];
    {
        const float* cinitf = (const float*)smem;
        #pragma unroll
        for (int mt = 0; mt < 2; mt++)
            #pragma unroll
            for (int h = 0; h < 2; h++)
                #pragma unroll
                for (int r = 0; r < 4; r++) {
                    int m = mt * 16 + lq * 4 + r, u = wv * 32 + h * 16 + l15;
                    c0r[mt][h][r] = cinitf[m * 256 + u];
                    c1r[mt][h][r] = cinitf[8192 + m * 256 + u];
                }
    }
    __syncthreads(); // cinit overlay dead

    const float* bias0 = (const float*)(ws + OFF_B0);
    const float* bias1 = (const float*)(ws + OFF_B1);
    float bs0[8], bs1[8];
    #pragma unroll
    for (int q = 0; q < 8; q++) {
        int col = (q >> 1) * 256 + wv * 32 + (q & 1) * 16 + l15;
        bs0[q] = bias0[col];
        bs1[q] = bias1[col];
    }
    // phase-C assignment: waves 0..3 -> (mt = wv>>1, nt = wv&1)
    const int pc_nt = wv & 1, pc_mt = wv >> 1;
    const int pc_col = pc_nt * 16 + l15;
    const float bpj = (wv < 4 && pc_col < 20) ? b_proj[pc_col] : 0.0f;

    // per-lane weight stream bases (fragment layout: tile base + lane*16)
    const char* W0hL = ws + OFF_WHH0 + lnoff;
    const char* W0xL = ws + OFF_WIH0 + lnoff;
    const char* W1xL = ws + OFF_WIH1 + lnoff;
    const char* W1hL = ws + OFF_WHH1 + lnoff;
    const char* wps_c = smem + SM_WPS;
    const char* h0c = smem + SM_H0;
    const char* h1c = smem + SM_H1;
    const char* xbc = smem + SM_XB;

    float* outp = out;

    // per-wave n-tile byte offsets (stride-8192 matrices); q = half*4+qq matches acc/bias map
    int ntb[8];
    #pragma unroll
    for (int q = 0; q < 8; q++)
        ntb[q] = ((q >> 2) * 32 + ((q & 3) >> 1) * 16 + wv * 2 + (q & 1)) * 8192;

    // W0x register-resident for all 512 steps (stride 1024 = ntb/8)
    bf16x8 wX[8];
    #pragma unroll
    for (int q = 0; q < 8; q++) wX[q] = *(const bf16x8*)(W0xL + (ntb[q] >> 3));

    f32x4 acc[8][2];
    bf16x8 wP0[8], wP1[8], a0, a1;

#define LOADW(Wbuf, Lbase, koff) do { _Pragma("unroll") \
    for (int q = 0; q < 8; q++) Wbuf[q] = *(const bf16x8*)((Lbase) + ntb[q] + (koff)); } while (0)
#define MFMA8(Wbuf) do { _Pragma("unroll") for (int q = 0; q < 8; q++) { \
    acc[q][0] = __builtin_amdgcn_mfma_f32_16x16x32_bf16(a0, Wbuf[q], acc[q][0], 0, 0, 0); \
    acc[q][1] = __builtin_amdgcn_mfma_f32_16x16x32_bf16(a1, Wbuf[q], acc[q][1], 0, 0, 0); } } while (0)
#define AFRAG(hsrc, ktv) do { \
    a0 = *(const bf16x8*)((hsrc) + l15 * 528 + (ktv) * 64 + lq * 16); \
    a1 = *(const bf16x8*)((hsrc) + (16 + l15) * 528 + (ktv) * 64 + lq * 16); } while (0)

    // phase C (waves 0..3): y(t-1) -> out, x(t) -> xb. Reads h1 (state of t-1), wps. Pure LDS.
    auto phaseC = [&](int t) {
        f32x4 py = {bpj, bpj, bpj, bpj};
        #pragma unroll
        for (int kt = 0; kt < 8; kt++) {
            bf16x8 ah = *(const bf16x8*)(h1c + (pc_mt * 16 + l15) * 528 + kt * 64 + lq * 16);
            bf16x8 wf = *(const bf16x8*)(wps_c + pc_nt * 8192 + kt * 1024 + lnoff);
            py = __builtin_amdgcn_mfma_f32_16x16x32_bf16(ah, wf, py, 0, 0, 0);
        }
        if (pc_col < 20) {
            #pragma unroll
            for (int r = 0; r < 4; r++) {
                int row = pc_mt * 16 + lq * 4 + r;
                outp[((size_t)(b0 + row) * TT + (t - 1)) * DD + pc_col] = py[r];
                xbh[row * 32 + pc_col] = __float2bfloat16(py[r]);
            }
        }
    };

    // ---- prologue: prefetch W0h kt0 ----
    LOADW(wP0, W0hL, 0);

    #pragma unroll 1
    for (int t = 0; t < TT; t++) {
        // ======== phase A: gates0 = bias0 + h0 @ W0h^T (+ x @ W0x^T) ========
        #pragma unroll
        for (int q = 0; q < 8; q++) {
            f32x4 v = {bs0[q], bs0[q], bs0[q], bs0[q]};
            acc[q][0] = v; acc[q][1] = v;
        }
        if (t > 0 && wv < 4) phaseC(t);
        #pragma unroll
        for (int kt = 0; kt < 8; kt += 2) {
            LOADW(wP1, W0hL, (kt + 1) * 1024);
            AFRAG(h0c, kt);     MFMA8(wP0);
            if (kt < 6) LOADW(wP0, W0hL, (kt + 2) * 1024);
            else        LOADW(wP0, W1xL, 0);           // next phase slot 0
            AFRAG(h0c, kt + 1); MFMA8(wP1);
        }
        __syncthreads();   // B1: all h0p reads done; xbh (phase C) visible

        // x-part: register-resident W0x, A = xb
        a0 = *(const bf16x8*)(xbc + l15 * 64 + lq * 16);
        a1 = *(const bf16x8*)(xbc + (16 + l15) * 64 + lq * 16);
        MFMA8(wX);

        // ---- EW-A: c0,h0 update (in place) ----
        #pragma unroll
        for (int mt = 0; mt < 2; mt++)
            #pragma unroll
            for (int h = 0; h < 2; h++)
                #pragma unroll
                for (int r = 0; r < 4; r++) {
                    float iv = acc[0 + h][mt][r], fv = acc[2 + h][mt][r];
                    float gv = acc[4 + h][mt][r], ov = acc[6 + h][mt][r];
                    float cn = sigf(fv) * c0r[mt][h][r] + sigf(iv) * tanhfast(gv);
                    float hn = sigf(ov) * tanhfast(cn);
                    c0r[mt][h][r] = cn;
                    h0p[(mt * 16 + lq * 4 + r) * 264 + wv * 32 + h * 16 + l15] = __float2bfloat16(hn);
                }
        __syncthreads();   // B2: h0_new visible

        // ======== phase B: gates1 = bias1 + h0_new @ W1x^T + h1 @ W1h^T ========
        #pragma unroll
        for (int q = 0; q < 8; q++) {
            f32x4 v = {bs1[q], bs1[q], bs1[q], bs1[q]};
            acc[q][0] = v; acc[q][1] = v;
        }
        #pragma unroll
        for (int kt = 0; kt < 8; kt += 2) {
            LOADW(wP1, W1xL, (kt + 1) * 1024);
            AFRAG(h0c, kt);     MFMA8(wP0);
            if (kt < 6) LOADW(wP0, W1xL, (kt + 2) * 1024);
            else        LOADW(wP0, W1hL, 0);
            AFRAG(h0c, kt + 1); MFMA8(wP1);
        }
        #pragma unroll
        for (int kt = 0; kt < 8; kt += 2) {
            LOADW(wP1, W1hL, (kt + 1) * 1024);
            AFRAG(h1c, kt);     MFMA8(wP0);
            if (kt < 6) LOADW(wP0, W1hL, (kt + 2) * 1024);
            else        LOADW(wP0, W0hL, 0);           // next step's phase A slot 0
            AFRAG(h1c, kt + 1); MFMA8(wP1);
        }
        __syncthreads();   // B3: all h1p reads done

        // ---- EW-B: c1,h1 update (in place) ----
        #pragma unroll
        for (int mt = 0; mt < 2; mt++)
            #pragma unroll
            for (int h = 0; h < 2; h++)
                #pragma unroll
                for (int r = 0; r < 4; r++) {
                    float iv = acc[0 + h][mt][r], fv = acc[2 + h][mt][r];
                    float gv = acc[4 + h][mt][r], ov = acc[6 + h][mt][r];
                    float cn = sigf(fv) * c1r[mt][h][r] + sigf(iv) * tanhfast(gv);
                    float hn = sigf(ov) * tanhfast(cn);
                    c1r[mt][h][r] = cn;
                    h1p[(mt * 16 + lq * 4 + r) * 264 + wv * 32 + h * 16 + l15] = __float2bfloat16(hn);
                }
        __syncthreads();   // B4: h1_new visible (next step's phase C / W1h part)
    }

    // final y(TT-1)
    if (wv < 4) phaseC(TT);

#undef LOADW
#undef MFMA8
#undef AFRAG
}

extern "C" void kernel_launch(void* const* d_in, const int* in_sizes, int n_in,
                              void* d_out, int out_size, void* d_ws, size_t ws_size,
                              hipStream_t stream) {
    const float* z      = (const float*)d_in[0];
    const float* w_lh   = (const float*)d_in[3];
    const float* b_lh   = (const float*)d_in[4];
    const float* w_lc   = (const float*)d_in[5];
    const float* b_lc   = (const float*)d_in[6];
    const float* w_ih0  = (const float*)d_in[7];
    const float* w_hh0  = (const float*)d_in[8];
    const float* b_ih0  = (const float*)d_in[9];
    const float* b_hh0  = (const float*)d_in[10];
    const float* w_ih1  = (const float*)d_in[11];
    const float* w_hh1  = (const float*)d_in[12];
    const float* b_ih1  = (const float*)d_in[13];
    const float* b_hh1  = (const float*)d_in[14];
    const float* w_proj = (const float*)d_in[15];
    const float* b_proj = (const float*)d_in[16];
    char* ws = (char*)d_ws;
    float* out = (float*)d_out;

    prep_kernel<<<3240, 256, 0, stream>>>(w_ih0, w_hh0, w_ih1, w_hh1, w_proj,
                                          b_ih0, b_hh0, b_ih1, b_hh1, ws);
    decoder_kernel<<<NBLK, 512, 0, stream>>>(z, w_lh, b_lh, w_lc, b_lc, b_proj, ws, out);
}

// Round 2
// 14862.352 us; speedup vs baseline: 1.8121x; 1.8121x over previous
//
#include <hip/hip_runtime.h>
#include <hip/hip_bf16.h>

#define NB 32
#define NBLK 64
#define TT 512
#define DD 20

using bf16x8 = __attribute__((ext_vector_type(8))) short;
using f32x4  = __attribute__((ext_vector_type(4))) float;

typedef __attribute__((address_space(3))) unsigned int lds_uint;
typedef __attribute__((address_space(1))) unsigned int glob_uint;

// workspace byte offsets (prep output)
#define OFF_WIH0  0          // 1024x20  -> 64 tiles x 1 kt (stride 1024)
#define OFF_WHH0  65536      // 1024x256 -> 64 tiles x 8 kt (stride 8192)
#define OFF_WIH1  589824
#define OFF_WHH1  1114112
#define OFF_WPROJ 1638400    // 20x256 -> 2 tiles x 8 kt
#define OFF_B0    1654784
#define OFF_B1    1658880

// smem layout (bytes): 3 x 32KB rotating panels (counted-vmcnt pipeline)
#define SM_PAN   0        // 3 panels x 32768 (cinit 64K overlay during init)
#define SM_H0    98304    // 32*264*2 = 16896 (single copy, in-place)
#define SM_H1    115200   // 16896
#define SM_XB    132096   // 32*32*2 = 2048
#define SM_WPS   134144   // 16384 (resident W_proj)
#define SM_ZB    150528   // 4096
#define SM_TOTAL 154624   // <= 160KB, 1 block/CU

__device__ __forceinline__ float sigf(float x) { return 1.0f / (1.0f + __expf(-x)); }
__device__ __forceinline__ float tanhfast(float x) { return 1.0f - 2.0f / (__expf(2.0f * x) + 1.0f); }

__device__ __forceinline__ void stage16(const char* g, const char* l) {
    __builtin_amdgcn_global_load_lds((glob_uint*)g, (lds_uint*)l, 16, 0, 0);
}

// interval barrier: counted vmcnt (4 newest = next-next panel stays in flight),
// raw s_barrier, IR + sched fences (rule #18 / m201 template pattern)
#define BARRIER_INT do { \
    asm volatile("s_waitcnt vmcnt(4) lgkmcnt(0)" ::: "memory"); \
    __builtin_amdgcn_s_barrier(); \
    asm volatile("" ::: "memory"); \
    __builtin_amdgcn_sched_barrier(0); \
} while (0)

// h-exchange barrier: publish LDS writes, do NOT drain vmcnt (stages stay in flight)
#define BARRIER_EW do { \
    asm volatile("s_waitcnt lgkmcnt(0)" ::: "memory"); \
    __builtin_amdgcn_s_barrier(); \
    asm volatile("" ::: "memory"); \
    __builtin_amdgcn_sched_barrier(0); \
} while (0)

// ---- prep: fp32 weights -> bf16, swizzled into MFMA B-fragment order ----
__global__ void prep_kernel(const float* __restrict__ wih0, const float* __restrict__ whh0,
                            const float* __restrict__ wih1, const float* __restrict__ whh1,
                            const float* __restrict__ wproj,
                            const float* __restrict__ bih0, const float* __restrict__ bhh0,
                            const float* __restrict__ bih1, const float* __restrict__ bhh1,
                            char* __restrict__ ws) {
    int idx = blockIdx.x * 256 + threadIdx.x;
    const float* src;
    __hip_bfloat16* dst;
    int e, N, K, nKt;
    if (idx < 32768)       { e = idx;          src = wih0;  N = 1024; K = 20;  nKt = 1; dst = (__hip_bfloat16*)(ws + OFF_WIH0); }
    else if (idx < 294912) { e = idx - 32768;  src = whh0;  N = 1024; K = 256; nKt = 8; dst = (__hip_bfloat16*)(ws + OFF_WHH0); }
    else if (idx < 557056) { e = idx - 294912; src = wih1;  N = 1024; K = 256; nKt = 8; dst = (__hip_bfloat16*)(ws + OFF_WIH1); }
    else if (idx < 819200) { e = idx - 557056; src = whh1;  N = 1024; K = 256; nKt = 8; dst = (__hip_bfloat16*)(ws + OFF_WHH1); }
    else if (idx < 827392) { e = idx - 819200; src = wproj; N = 20;   K = 256; nKt = 8; dst = (__hip_bfloat16*)(ws + OFF_WPROJ); }
    else if (idx < 828416) { int j = idx - 827392; ((float*)(ws + OFF_B0))[j] = bih0[j] + bhh0[j]; return; }
    else if (idx < 829440) { int j = idx - 828416; ((float*)(ws + OFF_B1))[j] = bih1[j] + bhh1[j]; return; }
    else return;
    int j    = e & 7;
    int lane = (e >> 3) & 63;
    int tile = e >> 9;
    int kt = tile % nKt;
    int nt = tile / nKt;
    int n = nt * 16 + (lane & 15);
    int k = kt * 32 + ((lane >> 4) << 3) + j;
    float v = (n < N && k < K) ? src[n * K + k] : 0.0f;
    dst[e] = __float2bfloat16(v);
}

// ---- persistent decoder: 64 blocks x 512 threads, 32 batch rows/block, 512 steps ----
// global_load_lds panel staging (L2-resident weights), 3 rotating buffers,
// counted vmcnt(4) so one panel stage is always in flight across barriers.
__global__ __launch_bounds__(512, 1) void decoder_kernel(
    const float* __restrict__ z, const float* __restrict__ w_lh, const float* __restrict__ b_lh,
    const float* __restrict__ w_lc, const float* __restrict__ b_lc,
    const float* __restrict__ b_proj, const char* __restrict__ ws,
    float* __restrict__ out) {

    __shared__ __align__(16) char smem[SM_TOTAL];

    const int tid = threadIdx.x;
    const int b0  = blockIdx.x * NB;

    __hip_bfloat16* h0p = (__hip_bfloat16*)(smem + SM_H0); // [m*264 + u]
    __hip_bfloat16* h1p = (__hip_bfloat16*)(smem + SM_H1);
    __hip_bfloat16* xbh = (__hip_bfloat16*)(smem + SM_XB); // [32][32]

    // ---- init: stage z, zero xb, stage W_proj ----
    {
        float* zbf = (float*)(smem + SM_ZB);
        zbf[tid]       = z[(b0 + (tid >> 5)) * 32 + (tid & 31)];
        int i2 = tid + 512;
        zbf[i2]        = z[(b0 + (i2 >> 5)) * 32 + (i2 & 31)];
        ((unsigned int*)(smem + SM_XB))[tid] = 0;  // 2048 B of zeros
        const bf16x8* sp = (const bf16x8*)(ws + OFF_WPROJ);
        bf16x8* dp = (bf16x8*)(smem + SM_WPS);
        dp[tid] = sp[tid];
        dp[tid + 512] = sp[tid + 512];
    }
    __syncthreads();

    // ---- h/c init (fp32 VALU, K=32): 32 rows x 512 cols ----
    {
        float* cinitf = (float*)smem;            // overlay in panel area: [2][32][256]
        const float* zbf = (const float*)(smem + SM_ZB);
        for (int ii = 0; ii < 32; ii++) {
            int pi = ii * 512 + tid;
            int b = pi >> 9, col = pi & 511;
            float dh = b_lh[col], dc = b_lc[col];
            #pragma unroll 8
            for (int k = 0; k < 32; k++) {
                float zv = zbf[b * 32 + k];
                dh += zv * w_lh[col * 32 + k];
                dc += zv * w_lc[col * 32 + k];
            }
            if (col < 256) { h0p[b * 264 + col]         = __float2bfloat16(dh); cinitf[b * 256 + col]                 = dc; }
            else           { h1p[b * 264 + (col - 256)] = __float2bfloat16(dh); cinitf[8192 + b * 256 + (col - 256)] = dc; }
        }
    }
    __syncthreads();

    const int wv = tid >> 6, ln = tid & 63;
    const int l15 = ln & 15, lq = ln >> 4;
    const int lnoff = ln * 16;

    // c-state lane-local: m = mt*16 + lq*4 + r, u = wv*32 + h*16 + l15
    float c0r[2][2][4], c1r[2][2][4];
    {
        const float* cinitf = (const float*)smem;
        #pragma unroll
        for (int mt = 0; mt < 2; mt++)
            #pragma unroll
            for (int h = 0; h < 2; h++)
                #pragma unroll
                for (int r = 0; r < 4; r++) {
                    int m = mt * 16 + lq * 4 + r, u = wv * 32 + h * 16 + l15;
                    c0r[mt][h][r] = cinitf[m * 256 + u];
                    c1r[mt][h][r] = cinitf[8192 + m * 256 + u];
                }
    }
    __syncthreads(); // cinit overlay dead; panel staging may now write

    const float* bias0 = (const float*)(ws + OFF_B0);
    const float* bias1 = (const float*)(ws + OFF_B1);
    float bs0[8], bs1[8];
    #pragma unroll
    for (int q = 0; q < 8; q++) {
        int col = (q >> 1) * 256 + wv * 32 + (q & 1) * 16 + l15;
        bs0[q] = bias0[col];
        bs1[q] = bias1[col];
    }
    // phase-C assignment: waves 0..3 -> (mt = wv>>1, nt = wv&1)
    const int pc_nt = wv & 1, pc_mt = wv >> 1;
    const int pc_col = pc_nt * 16 + l15;
    const float bpj = (wv < 4 && pc_col < 20) ? b_proj[pc_col] : 0.0f;

    const char* W0x = ws + OFF_WIH0;
    const char* W0h = ws + OFF_WHH0;
    const char* W1x = ws + OFF_WIH1;
    const char* W1h = ws + OFF_WHH1;
    const char* wps_c = smem + SM_WPS;
    const char* h0c = smem + SM_H0;
    const char* h1c = smem + SM_H1;
    const char* xbc = smem + SM_XB;

    float* outp = out;

    // stage panel u (0..49) into buffer bidx; wave wv stages tiles wv*4..wv*4+3.
    // u<16: W0h kt=u>>1 | u=16,17: W0x | u<34: W1x | else: W1h. half = u&1 always.
    auto stageU = [&](int u, int bidx) {
        const char* base; int stride, kt;
        const int half = u & 1;
        if (u < 16)      { base = W0h; stride = 8192; kt = u >> 1; }
        else if (u < 18) { base = W0x; stride = 1024; kt = 0; }
        else if (u < 34) { base = W1x; stride = 8192; kt = (u - 18) >> 1; }
        else             { base = W1h; stride = 8192; kt = (u - 34) >> 1; }
        const char* gsrc = base + (half * 32 + wv * 4) * stride + kt * 1024 + lnoff;
        char* ldst = smem + SM_PAN + bidx * 32768 + (wv * 4) * 1024;
        #pragma unroll
        for (int j = 0; j < 4; j++)
            stage16(gsrc + j * stride, ldst + j * 1024);
    };

    f32x4 acc[8][2];

    // compute one panel from buffer cb: q = half*4 + qq, both m-tiles
    auto panelCompute = [&](int cb, int kt, int half, const char* hsrc, bool isX) {
        const char* pb = smem + SM_PAN + cb * 32768;
        bf16x8 af0, af1;
        if (isX) {
            af0 = *(const bf16x8*)(xbc + l15 * 64 + lq * 16);
            af1 = *(const bf16x8*)(xbc + (16 + l15) * 64 + lq * 16);
        } else {
            af0 = *(const bf16x8*)(hsrc + l15 * 528 + kt * 64 + lq * 16);
            af1 = *(const bf16x8*)(hsrc + (16 + l15) * 528 + kt * 64 + lq * 16);
        }
        #pragma unroll
        for (int qq = 0; qq < 4; qq++) {
            int lt = (qq >> 1) * 16 + wv * 2 + (qq & 1);
            bf16x8 w = *(const bf16x8*)(pb + lt * 1024 + lnoff);
            acc[half * 4 + qq][0] = __builtin_amdgcn_mfma_f32_16x16x32_bf16(af0, w, acc[half * 4 + qq][0], 0, 0, 0);
            acc[half * 4 + qq][1] = __builtin_amdgcn_mfma_f32_16x16x32_bf16(af1, w, acc[half * 4 + qq][1], 0, 0, 0);
        }
    };

    // phase C (waves 0..3): y(t-1) -> out, x(t) -> xb. Reads h1 (state of t-1), wps. Pure LDS.
    auto phaseC = [&](int t) {
        f32x4 py = {bpj, bpj, bpj, bpj};
        #pragma unroll
        for (int kt = 0; kt < 8; kt++) {
            bf16x8 ah = *(const bf16x8*)(h1c + (pc_mt * 16 + l15) * 528 + kt * 64 + lq * 16);
            bf16x8 wf = *(const bf16x8*)(wps_c + pc_nt * 8192 + kt * 1024 + lnoff);
            py = __builtin_amdgcn_mfma_f32_16x16x32_bf16(ah, wf, py, 0, 0, 0);
        }
        if (pc_col < 20) {
            #pragma unroll
            for (int r = 0; r < 4; r++) {
                int row = pc_mt * 16 + lq * 4 + r;
                outp[((size_t)(b0 + row) * TT + (t - 1)) * DD + pc_col] = py[r];
                xbh[row * 32 + pc_col] = __float2bfloat16(py[r]);
            }
        }
    };

    // ---- prologue: stage panels 0,1 into buffers 0,1; publish panel 0 ----
    int cb = 0;
    stageU(0, 0);
    stageU(1, 1);
    asm volatile("s_waitcnt vmcnt(4)" ::: "memory");   // panel 0 landed (own loads)
    __builtin_amdgcn_s_barrier();                       // publish across waves
    asm volatile("" ::: "memory");
    __builtin_amdgcn_sched_barrier(0);

    #pragma unroll 1
    for (int t = 0; t < TT; t++) {
        // ======== phase A: gates0 = bias0 + h0 @ W0h^T (+ x @ W0x^T) ========
        #pragma unroll
        for (int q = 0; q < 8; q++) {
            f32x4 v = {bs0[q], bs0[q], bs0[q], bs0[q]};
            acc[q][0] = v; acc[q][1] = v;
        }
        #pragma unroll 2
        for (int u = 0; u < 16; ++u) {
            stageU(u + 2, cb ? cb - 1 : 2);
            if (u == 0 && t > 0 && wv < 4) phaseC(t);
            panelCompute(cb, u >> 1, u & 1, h0c, false);
            BARRIER_INT;
            cb = (cb == 2) ? 0 : cb + 1;
        }
        // u = 16, 17: W0x halves, A = xb
        stageU(18, cb ? cb - 1 : 2);
        panelCompute(cb, 0, 0, nullptr, true);
        BARRIER_INT;
        cb = (cb == 2) ? 0 : cb + 1;
        stageU(19, cb ? cb - 1 : 2);
        panelCompute(cb, 0, 1, nullptr, true);
        BARRIER_INT;
        cb = (cb == 2) ? 0 : cb + 1;

        // ---- EW-A: c0,h0 update (in place) ----
        #pragma unroll
        for (int mt = 0; mt < 2; mt++)
            #pragma unroll
            for (int h = 0; h < 2; h++)
                #pragma unroll
                for (int r = 0; r < 4; r++) {
                    float iv = acc[0 + h][mt][r], fv = acc[2 + h][mt][r];
                    float gv = acc[4 + h][mt][r], ov = acc[6 + h][mt][r];
                    float cn = sigf(fv) * c0r[mt][h][r] + sigf(iv) * tanhfast(gv);
                    float hn = sigf(ov) * tanhfast(cn);
                    c0r[mt][h][r] = cn;
                    h0p[(mt * 16 + lq * 4 + r) * 264 + wv * 32 + h * 16 + l15] = __float2bfloat16(hn);
                }
        BARRIER_EW;   // h0_new visible; stage loads for u=18,19 stay in flight

        // ======== phase B: gates1 = bias1 + h0_new @ W1x^T + h1 @ W1h^T ========
        #pragma unroll
        for (int q = 0; q < 8; q++) {
            f32x4 v = {bs1[q], bs1[q], bs1[q], bs1[q]};
            acc[q][0] = v; acc[q][1] = v;
        }
        #pragma unroll 2
        for (int u = 18; u < 50; ++u) {
            int un = u + 2; if (un >= 50) un -= 50;   // 48,49 chain next step's panels 0,1
            stageU(un, cb ? cb - 1 : 2);
            int rel = (u - 18) & 15;
            panelCompute(cb, rel >> 1, u & 1, (u < 34) ? h0c : h1c, false);
            BARRIER_INT;
            cb = (cb == 2) ? 0 : cb + 1;
        }

        // ---- EW-B: c1,h1 update (in place) ----
        #pragma unroll
        for (int mt = 0; mt < 2; mt++)
            #pragma unroll
            for (int h = 0; h < 2; h++)
                #pragma unroll
                for (int r = 0; r < 4; r++) {
                    float iv = acc[0 + h][mt][r], fv = acc[2 + h][mt][r];
                    float gv = acc[4 + h][mt][r], ov = acc[6 + h][mt][r];
                    float cn = sigf(fv) * c1r[mt][h][r] + sigf(iv) * tanhfast(gv);
                    float hn = sigf(ov) * tanhfast(cn);
                    c1r[mt][h][r] = cn;
                    h1p[(mt * 16 + lq * 4 + r) * 264 + wv * 32 + h * 16 + l15] = __float2bfloat16(hn);
                }
        BARRIER_EW;   // h1_new visible (next step's phase C / W1h part)
    }

    // final y(TT-1)
    if (wv < 4) phaseC(TT);
}

extern "C" void kernel_launch(void* const* d_in, const int* in_sizes, int n_in,
                              void* d_out, int out_size, void* d_ws, size_t ws_size,
                              hipStream_t stream) {
    const float* z      = (const float*)d_in[0];
    const float* w_lh   = (const float*)d_in[3];
    const float* b_lh   = (const float*)d_in[4];
    const float* w_lc   = (const float*)d_in[5];
    const float* b_lc   = (const float*)d_in[6];
    const float* w_ih0  = (const float*)d_in[7];
    const float* w_hh0  = (const float*)d_in[8];
    const float* b_ih0  = (const float*)d_in[9];
    const float* b_hh0  = (const float*)d_in[10];
    const float* w_ih1  = (const float*)d_in[11];
    const float* w_hh1  = (const float*)d_in[12];
    const float* b_ih1  = (const float*)d_in[13];
    const float* b_hh1  = (const float*)d_in[14];
    const float* w_proj = (const float*)d_in[15];
    const float* b_proj = (const float*)d_in[16];
    char* ws = (char*)d_ws;
    float* out = (float*)d_out;

    prep_kernel<<<3240, 256, 0, stream>>>(w_ih0, w_hh0, w_ih1, w_hh1, w_proj,
                                          b_ih0, b_hh0, b_ih1, b_hh1, ws);
    decoder_kernel<<<NBLK, 512, 0, stream>>>(z, w_lh, b_lh, w_lc, b_lc, b_proj, ws, out);
}

// Round 3
// 11135.271 us; speedup vs baseline: 2.4186x; 1.3347x over previous
//
#include <hip/hip_runtime.h>
#include <hip/hip_bf16.h>

#define NB 32
#define NBLK 64
#define TT 512
#define DD 20

using bf16x8 = __attribute__((ext_vector_type(8))) short;
using f32x4  = __attribute__((ext_vector_type(4))) float;

typedef __attribute__((address_space(3))) unsigned int lds_uint;
typedef __attribute__((address_space(1))) unsigned int glob_uint;

// workspace: per-wave-linear weight stream.
// stream tile (s, wv) at byte s*8192 + wv*1024, s = panel*4 + qq, panel u = 0..49:
//   u<16: W0h kt=u>>1 | u=16,17: W0x kt=0 | u<34: W1x kt=(u-18)>>1 | else W1h kt=(u-34)>>1
//   half=u&1; n-tile NT = half*32 + (qq>>1)*16 + wv*2 + (qq&1)
#define OFF_WSTR  0          // 1,638,400 B
#define OFF_WPROJ 1638400    // 20x256 -> 2 tiles x 8 kt
#define OFF_B0    1654784
#define OFF_B1    1658880
#define WSTR_BYTES 1638400

// smem layout (bytes)
#define SM_RING  0        // 8 waves x 3 panel-slots x 4KB = 96KB (cinit 64K overlay at init)
#define SM_H0    98304    // 32*264*2 = 16896 (single copy, in-place)
#define SM_H1    115200   // 16896
#define SM_XB    132096   // 32*32*2 = 2048
#define SM_WPS   134144   // 16384 (resident W_proj)
#define SM_ZB    150528   // 4096
#define SM_TOTAL 154624

__device__ __forceinline__ float sigf(float x) { return 1.0f / (1.0f + __expf(-x)); }
__device__ __forceinline__ float tanhfast(float x) { return 1.0f - 2.0f / (__expf(2.0f * x) + 1.0f); }

__device__ __forceinline__ void stage16(const char* g, const char* l) {
    __builtin_amdgcn_global_load_lds((glob_uint*)g, (lds_uint*)l, 16, 0, 0);
}

// LDS-publish barrier: drain LDS ops, raw s_barrier. vmcnt NOT drained:
// per-wave weight-stage FIFO stays in flight across all barriers.
#define BARRIER_LK do { \
    asm volatile("s_waitcnt lgkmcnt(0)" ::: "memory"); \
    __builtin_amdgcn_s_barrier(); \
    asm volatile("" ::: "memory"); \
    __builtin_amdgcn_sched_barrier(0); \
} while (0)

// ---- prep: fp32 weights -> bf16, swizzled into per-wave-linear MFMA B-fragment stream ----
__global__ void prep_kernel(const float* __restrict__ wih0, const float* __restrict__ whh0,
                            const float* __restrict__ wih1, const float* __restrict__ whh1,
                            const float* __restrict__ wproj,
                            const float* __restrict__ bih0, const float* __restrict__ bhh0,
                            const float* __restrict__ bih1, const float* __restrict__ bhh1,
                            char* __restrict__ ws) {
    int idx = blockIdx.x * 256 + threadIdx.x;
    if (idx < 819200) {
        // weight stream element: s = idx>>12, wv = (idx>>9)&7, e2 = idx&511
        int s  = idx >> 12;
        int wv = (idx >> 9) & 7;
        int e2 = idx & 511;
        int u = s >> 2, qq = s & 3, half = u & 1;
        const float* src; int K, kt;
        if (u < 16)      { src = whh0; K = 256; kt = u >> 1; }
        else if (u < 18) { src = wih0; K = 20;  kt = 0; }
        else if (u < 34) { src = wih1; K = 256; kt = (u - 18) >> 1; }
        else             { src = whh1; K = 256; kt = (u - 34) >> 1; }
        int NT = half * 32 + (qq >> 1) * 16 + wv * 2 + (qq & 1);
        int j = e2 & 7, lane = e2 >> 3;
        int n = NT * 16 + (lane & 15);
        int k = kt * 32 + ((lane >> 4) << 3) + j;
        float v = (k < K) ? src[n * K + k] : 0.0f;
        ((__hip_bfloat16*)(ws + OFF_WSTR))[idx] = __float2bfloat16(v);
    } else if (idx < 827392) {
        // W_proj: 20x256 -> 2 n-tiles x 8 kt, tile-linear
        int e = idx - 819200;
        int j = e & 7, lane = (e >> 3) & 63, tile = e >> 9;
        int kt = tile & 7, nt = tile >> 3;
        int n = nt * 16 + (lane & 15);
        int k = kt * 32 + ((lane >> 4) << 3) + j;
        float v = (n < 20) ? wproj[n * 256 + k] : 0.0f;
        ((__hip_bfloat16*)(ws + OFF_WPROJ))[e] = __float2bfloat16(v);
    } else if (idx < 828416) {
        int j = idx - 827392; ((float*)(ws + OFF_B0))[j] = bih0[j] + bhh0[j];
    } else if (idx < 829440) {
        int j = idx - 828416; ((float*)(ws + OFF_B1))[j] = bih1[j] + bhh1[j];
    }
}

// ---- persistent decoder: 64 blocks x 512 threads, 32 batch rows/block, 512 steps ----
// Each wave self-stages its own weight tiles (global_load_lds) into a private
// 3-slot LDS ring; per-panel counted s_waitcnt vmcnt(8). 5 barriers per step.
__global__ __launch_bounds__(512, 1) void decoder_kernel(
    const float* __restrict__ z, const float* __restrict__ w_lh, const float* __restrict__ b_lh,
    const float* __restrict__ w_lc, const float* __restrict__ b_lc,
    const float* __restrict__ b_proj, const char* __restrict__ ws,
    float* __restrict__ out) {

    __shared__ __align__(16) char smem[SM_TOTAL];

    const int tid = threadIdx.x;
    const int b0  = blockIdx.x * NB;

    __hip_bfloat16* h0p = (__hip_bfloat16*)(smem + SM_H0); // [m*264 + u]
    __hip_bfloat16* h1p = (__hip_bfloat16*)(smem + SM_H1);
    __hip_bfloat16* xbh = (__hip_bfloat16*)(smem + SM_XB); // [32][32]

    // ---- init: stage z, zero xb, stage W_proj ----
    {
        float* zbf = (float*)(smem + SM_ZB);
        zbf[tid]       = z[(b0 + (tid >> 5)) * 32 + (tid & 31)];
        int i2 = tid + 512;
        zbf[i2]        = z[(b0 + (i2 >> 5)) * 32 + (i2 & 31)];
        ((unsigned int*)(smem + SM_XB))[tid] = 0;  // 2048 B of zeros
        const bf16x8* sp = (const bf16x8*)(ws + OFF_WPROJ);
        bf16x8* dp = (bf16x8*)(smem + SM_WPS);
        dp[tid] = sp[tid];
        dp[tid + 512] = sp[tid + 512];
    }
    __syncthreads();

    // ---- h/c init (fp32 VALU, K=32): 32 rows x 512 cols ----
    {
        float* cinitf = (float*)smem;            // overlay in ring area: [2][32][256]
        const float* zbf = (const float*)(smem + SM_ZB);
        for (int ii = 0; ii < 32; ii++) {
            int pi = ii * 512 + tid;
            int b = pi >> 9, col = pi & 511;
            float dh = b_lh[col], dc = b_lc[col];
            #pragma unroll 8
            for (int k = 0; k < 32; k++) {
                float zv = zbf[b * 32 + k];
                dh += zv * w_lh[col * 32 + k];
                dc += zv * w_lc[col * 32 + k];
            }
            if (col < 256) { h0p[b * 264 + col]         = __float2bfloat16(dh); cinitf[b * 256 + col]                 = dc; }
            else           { h1p[b * 264 + (col - 256)] = __float2bfloat16(dh); cinitf[8192 + b * 256 + (col - 256)] = dc; }
        }
    }
    __syncthreads();

    const int wv = tid >> 6, ln = tid & 63;
    const int l15 = ln & 15, lq = ln >> 4;
    const int lnoff = ln * 16;

    // c-state lane-local: m = mt*16 + lq*4 + r, u = wv*32 + h*16 + l15
    float c0r[2][2][4], c1r[2][2][4];
    {
        const float* cinitf = (const float*)smem;
        #pragma unroll
        for (int mt = 0; mt < 2; mt++)
            #pragma unroll
            for (int h = 0; h < 2; h++)
                #pragma unroll
                for (int r = 0; r < 4; r++) {
                    int m = mt * 16 + lq * 4 + r, u = wv * 32 + h * 16 + l15;
                    c0r[mt][h][r] = cinitf[m * 256 + u];
                    c1r[mt][h][r] = cinitf[8192 + m * 256 + u];
                }
    }
    __syncthreads(); // cinit overlay dead; ring staging may now write

    const float* bias0 = (const float*)(ws + OFF_B0);
    const float* bias1 = (const float*)(ws + OFF_B1);
    float bs0[8], bs1[8];
    #pragma unroll
    for (int q = 0; q < 8; q++) {
        int col = (q >> 1) * 256 + wv * 32 + (q & 1) * 16 + l15;
        bs0[q] = bias0[col];
        bs1[q] = bias1[col];
    }
    // phase-C assignment: waves 0..3 -> (mt = wv>>1, nt = wv&1)
    const int pc_nt = wv & 1, pc_mt = wv >> 1;
    const int pc_col = pc_nt * 16 + l15;
    const float bpj = (wv < 4 && pc_col < 20) ? b_proj[pc_col] : 0.0f;

    const char* wps_c = smem + SM_WPS;
    const char* h0c = smem + SM_H0;
    const char* h1c = smem + SM_H1;
    const char* xbc = smem + SM_XB;

    float* outp = out;

    // ---- per-wave weight stream state ----
    const char* wgl   = ws + OFF_WSTR + wv * 1024 + lnoff;   // per-lane global src base
    char*       ringb = smem + SM_RING + wv * 12288;          // wave-uniform LDS ring base
    const char* ringc = smem + SM_RING + wv * 12288 + lnoff;  // per-lane ring read base
    int sOff = 2 * 32768;   // global byte offset of next panel to stage (panel 2)
    int slS  = 2;           // ring slot of next panel to stage
    int slR  = 0;           // ring slot of next panel to read

    f32x4 acc[8][2];

    // one panel: stage panel p+2, vmcnt(8) -> panel p landed, 4 w-tiles + 8 MFMA.
    // qbase must be a literal (0 or 4) at each call site (static acc indexing).
    auto doPanel = [&](const char* hsrc, int kt, bool isX, int qbase) {
        bf16x8 af0, af1;
        if (isX) {
            af0 = *(const bf16x8*)(xbc + l15 * 64 + lq * 16);
            af1 = *(const bf16x8*)(xbc + (16 + l15) * 64 + lq * 16);
        } else {
            af0 = *(const bf16x8*)(hsrc + l15 * 528 + kt * 64 + lq * 16);
            af1 = *(const bf16x8*)(hsrc + (16 + l15) * 528 + kt * 64 + lq * 16);
        }
        #pragma unroll
        for (int j = 0; j < 4; j++)
            stage16(wgl + (sOff + j * 8192), ringb + slS * 4096 + j * 1024);
        sOff += 32768; if (sOff >= WSTR_BYTES) sOff = 0;
        slS = (slS == 2) ? 0 : slS + 1;
        asm volatile("s_waitcnt vmcnt(8)" ::: "memory");   // panels p+1,p+2 in flight; p landed
        __builtin_amdgcn_sched_barrier(0);
        const char* rb = ringc + slR * 4096;
        slR = (slR == 2) ? 0 : slR + 1;
        bf16x8 w0 = *(const bf16x8*)(rb);
        bf16x8 w1 = *(const bf16x8*)(rb + 1024);
        bf16x8 w2 = *(const bf16x8*)(rb + 2048);
        bf16x8 w3 = *(const bf16x8*)(rb + 3072);
        acc[qbase + 0][0] = __builtin_amdgcn_mfma_f32_16x16x32_bf16(af0, w0, acc[qbase + 0][0], 0, 0, 0);
        acc[qbase + 0][1] = __builtin_amdgcn_mfma_f32_16x16x32_bf16(af1, w0, acc[qbase + 0][1], 0, 0, 0);
        acc[qbase + 1][0] = __builtin_amdgcn_mfma_f32_16x16x32_bf16(af0, w1, acc[qbase + 1][0], 0, 0, 0);
        acc[qbase + 1][1] = __builtin_amdgcn_mfma_f32_16x16x32_bf16(af1, w1, acc[qbase + 1][1], 0, 0, 0);
        acc[qbase + 2][0] = __builtin_amdgcn_mfma_f32_16x16x32_bf16(af0, w2, acc[qbase + 2][0], 0, 0, 0);
        acc[qbase + 2][1] = __builtin_amdgcn_mfma_f32_16x16x32_bf16(af1, w2, acc[qbase + 2][1], 0, 0, 0);
        acc[qbase + 3][0] = __builtin_amdgcn_mfma_f32_16x16x32_bf16(af0, w3, acc[qbase + 3][0], 0, 0, 0);
        acc[qbase + 3][1] = __builtin_amdgcn_mfma_f32_16x16x32_bf16(af1, w3, acc[qbase + 3][1], 0, 0, 0);
    };

    // phase C (waves 0..3): y(t-1) -> out, x(t) -> xb. Reads h1 (state of t-1), wps. Pure LDS.
    auto phaseC = [&](int t) {
        f32x4 py = {bpj, bpj, bpj, bpj};
        #pragma unroll
        for (int kt = 0; kt < 8; kt++) {
            bf16x8 ah = *(const bf16x8*)(h1c + (pc_mt * 16 + l15) * 528 + kt * 64 + lq * 16);
            bf16x8 wf = *(const bf16x8*)(wps_c + pc_nt * 8192 + kt * 1024 + lnoff);
            py = __builtin_amdgcn_mfma_f32_16x16x32_bf16(ah, wf, py, 0, 0, 0);
        }
        if (pc_col < 20) {
            #pragma unroll
            for (int r = 0; r < 4; r++) {
                int row = pc_mt * 16 + lq * 4 + r;
                outp[((size_t)(b0 + row) * TT + (t - 1)) * DD + pc_col] = py[r];
                xbh[row * 32 + pc_col] = __float2bfloat16(py[r]);
            }
        }
    };

    // ---- prologue: stage panels 0,1 into slots 0,1 ----
    #pragma unroll
    for (int j = 0; j < 4; j++) stage16(wgl + j * 8192,         ringb + j * 1024);
    #pragma unroll
    for (int j = 0; j < 4; j++) stage16(wgl + 32768 + j * 8192, ringb + 4096 + j * 1024);

    #pragma unroll 1
    for (int t = 0; t < TT; t++) {
        // ======== phase A: gates0 = bias0 + h0 @ W0h^T + x @ W0x^T ========
        #pragma unroll
        for (int q = 0; q < 8; q++) {
            f32x4 v = {bs0[q], bs0[q], bs0[q], bs0[q]};
            acc[q][0] = v; acc[q][1] = v;
        }
        if (t > 0 && wv < 4) phaseC(t);
        // panels 0..13: W0h kt 0..6
        #pragma unroll 1
        for (int uu = 0; uu < 7; uu++) {
            doPanel(h0c, uu, false, 0);
            doPanel(h0c, uu, false, 4);
        }
        BARRIER_LK;   // xb (phase C) published before W0x panels
        doPanel(h0c, 7, false, 0);     // u=14
        doPanel(h0c, 7, false, 4);     // u=15
        doPanel(xbc, 0, true,  0);     // u=16: x @ W0x, half 0
        doPanel(xbc, 0, true,  4);     // u=17: half 1
        BARRIER_LK;   // pre-EW-A: all h0/xb reads done

        // ---- EW-A: c0,h0 update (in place) ----
        #pragma unroll
        for (int mt = 0; mt < 2; mt++)
            #pragma unroll
            for (int h = 0; h < 2; h++)
                #pragma unroll
                for (int r = 0; r < 4; r++) {
                    float iv = acc[0 + h][mt][r], fv = acc[2 + h][mt][r];
                    float gv = acc[4 + h][mt][r], ov = acc[6 + h][mt][r];
                    float cn = sigf(fv) * c0r[mt][h][r] + sigf(iv) * tanhfast(gv);
                    float hn = sigf(ov) * tanhfast(cn);
                    c0r[mt][h][r] = cn;
                    h0p[(mt * 16 + lq * 4 + r) * 264 + wv * 32 + h * 16 + l15] = __float2bfloat16(hn);
                }
        BARRIER_LK;   // h0_new visible

        // ======== phase B: gates1 = bias1 + h0_new @ W1x^T + h1 @ W1h^T ========
        #pragma unroll
        for (int q = 0; q < 8; q++) {
            f32x4 v = {bs1[q], bs1[q], bs1[q], bs1[q]};
            acc[q][0] = v; acc[q][1] = v;
        }
        #pragma unroll 1
        for (int uu = 0; uu < 8; uu++) {      // panels 18..33: W1x
            doPanel(h0c, uu, false, 0);
            doPanel(h0c, uu, false, 4);
        }
        #pragma unroll 1
        for (int uu = 0; uu < 8; uu++) {      // panels 34..49: W1h
            doPanel(h1c, uu, false, 0);
            doPanel(h1c, uu, false, 4);
        }
        BARRIER_LK;   // pre-EW-B: all h1 reads done

        // ---- EW-B: c1,h1 update (in place) ----
        #pragma unroll
        for (int mt = 0; mt < 2; mt++)
            #pragma unroll
            for (int h = 0; h < 2; h++)
                #pragma unroll
                for (int r = 0; r < 4; r++) {
                    float iv = acc[0 + h][mt][r], fv = acc[2 + h][mt][r];
                    float gv = acc[4 + h][mt][r], ov = acc[6 + h][mt][r];
                    float cn = sigf(fv) * c1r[mt][h][r] + sigf(iv) * tanhfast(gv);
                    float hn = sigf(ov) * tanhfast(cn);
                    c1r[mt][h][r] = cn;
                    h1p[(mt * 16 + lq * 4 + r) * 264 + wv * 32 + h * 16 + l15] = __float2bfloat16(hn);
                }
        BARRIER_LK;   // h1_new visible (next step's phase C / W1h reads)
    }

    // final y(TT-1)
    if (wv < 4) phaseC(TT);
}

extern "C" void kernel_launch(void* const* d_in, const int* in_sizes, int n_in,
                              void* d_out, int out_size, void* d_ws, size_t ws_size,
                              hipStream_t stream) {
    const float* z      = (const float*)d_in[0];
    const float* w_lh   = (const float*)d_in[3];
    const float* b_lh   = (const float*)d_in[4];
    const float* w_lc   = (const float*)d_in[5];
    const float* b_lc   = (const float*)d_in[6];
    const float* w_ih0  = (const float*)d_in[7];
    const float* w_hh0  = (const float*)d_in[8];
    const float* b_ih0  = (const float*)d_in[9];
    const float* b_hh0  = (const float*)d_in[10];
    const float* w_ih1  = (const float*)d_in[11];
    const float* w_hh1  = (const float*)d_in[12];
    const float* b_ih1  = (const float*)d_in[13];
    const float* b_hh1  = (const float*)d_in[14];
    const float* w_proj = (const float*)d_in[15];
    const float* b_proj = (const float*)d_in[16];
    char* ws = (char*)d_ws;
    float* out = (float*)d_out;

    prep_kernel<<<3240, 256, 0, stream>>>(w_ih0, w_hh0, w_ih1, w_hh1, w_proj,
                                          b_ih0, b_hh0, b_ih1, b_hh1, ws);
    decoder_kernel<<<NBLK, 512, 0, stream>>>(z, w_lh, b_lh, w_lc, b_lc, b_proj, ws, out);
}